// Round 3
// baseline (142.789 us; speedup 1.0000x reference)
//
#include <hip/hip_runtime.h>
#include <hip/hip_bf16.h>
#include <math.h>

#define N_NODES 50000
#define N_EDGES 800000
#define NFEAT 256
#define NHID 128
#define NCLASS 32
#define STRIDE 48  // padded CSR row stride; slot 0 = self loop
#define G1B 782    // ceil(N_NODES/64) gemm1 blocks

#define INFF __builtin_inff()

typedef unsigned short ushort_t;
typedef unsigned int uint_t;
typedef __bf16 bf16x8 __attribute__((ext_vector_type(8)));
typedef float f32x4 __attribute__((ext_vector_type(4)));
typedef unsigned short u16x2 __attribute__((ext_vector_type(2)));

__device__ __forceinline__ float bf2f(ushort_t u) {
  union { unsigned int i; float f; } c;
  c.i = ((unsigned int)u) << 16;
  return c.f;
}
__device__ __forceinline__ ushort_t f2bf(float f) {
  unsigned int x = __float_as_uint(f);
  unsigned int r = (x + 0x7fff + ((x >> 16) & 1)) >> 16;  // RNE
  return (ushort_t)r;
}
// monotone bf16-bits -> sortable-u16 (unsigned order == float order)
__device__ __forceinline__ ushort_t bf2sort(ushort_t b) {
  return b ^ ((b & 0x8000) ? 0xFFFFu : 0x8000u);
}
__device__ __forceinline__ ushort_t sort2bf(ushort_t s) {
  return s ^ ((s & 0x8000) ? 0x8000u : 0xFFFFu);
}

// ======================= scatter_k (R0 logic, own dispatch for attribution) =======================

__global__ __launch_bounds__(256) void scatter_k(const int* __restrict__ src,
                                                 const int* __restrict__ dst,
                                                 int* __restrict__ cur,
                                                 ushort_t* __restrict__ adjw) {
  int i = blockIdx.x * 256 + threadIdx.x;
  if (i < N_EDGES) {
    int s = src[i], d = dst[i];
    if (s != d) {
      int p = atomicAdd(&cur[d], 1);
      if (p < STRIDE - 1) adjw[d * STRIDE + 1 + p] = (ushort_t)s;
    }
  } else {
    int v = i - N_EDGES;
    if (v < N_NODES) adjw[v * STRIDE] = (ushort_t)v;  // self loop in slot 0
  }
}

// ======================= GEMM1 (MFMA): h1 = X @ W1 -> sortable-u16 =======================
// 64x128 tile, BK=32, 4 waves (32x64 each).

__global__ __launch_bounds__(256) void gemm1_k(const float* __restrict__ X,
                                               const float* __restrict__ W,
                                               ushort_t* __restrict__ H1) {
  __shared__ ushort_t As[64][40];   // [row][k], +8 pad
  __shared__ ushort_t Bs[128][40];  // [col][k] (W1 transposed)
  int bid = blockIdx.x;
  int tid = threadIdx.x;

  int rb = bid * 64;
  int lane = tid & 63, wid = tid >> 6;
  int wm = wid >> 1, wn = wid & 1;   // wm: 32-row half, wn: 64-col half
  int lrow = lane & 15, lk = (lane >> 4) * 8;
  int arow = tid >> 2, akq = (tid & 3) * 8;  // A staging: 64 rows x 4 chunks of 8
  int bn = tid & 127, bkh = tid >> 7;        // B staging: col, 16-wide k-half

  f32x4 acc[2][4];
#pragma unroll
  for (int m = 0; m < 2; ++m)
#pragma unroll
    for (int n = 0; n < 4; ++n) acc[m][n] = (f32x4){0.f, 0.f, 0.f, 0.f};

  for (int kc = 0; kc < NFEAT; kc += 32) {
    // stage A: 64 rows x 32 k, f32 -> bf16 (8 elems per thread)
    {
      int grow = rb + arow;
      bf16x8 p;
      if (grow < N_NODES) {
        const float* gp = X + (size_t)grow * NFEAT + kc + akq;
        float4 v0 = *reinterpret_cast<const float4*>(gp);
        float4 v1 = *reinterpret_cast<const float4*>(gp + 4);
        p[0] = (__bf16)v0.x; p[1] = (__bf16)v0.y; p[2] = (__bf16)v0.z; p[3] = (__bf16)v0.w;
        p[4] = (__bf16)v1.x; p[5] = (__bf16)v1.y; p[6] = (__bf16)v1.z; p[7] = (__bf16)v1.w;
      } else {
        p = (bf16x8)(__bf16)0.f;
      }
      *reinterpret_cast<bf16x8*>(&As[arow][akq]) = p;
    }
    // stage B transposed: Bs[n][k] <- W[kc+k][n]
    {
      const float* gp = W + (size_t)(kc + bkh * 16) * NHID + bn;
      bf16x8 p0, p1;
#pragma unroll
      for (int j = 0; j < 8; ++j) p0[j] = (__bf16)gp[(size_t)j * NHID];
#pragma unroll
      for (int j = 0; j < 8; ++j) p1[j] = (__bf16)gp[(size_t)(8 + j) * NHID];
      *reinterpret_cast<bf16x8*>(&Bs[bn][bkh * 16]) = p0;
      *reinterpret_cast<bf16x8*>(&Bs[bn][bkh * 16 + 8]) = p1;
    }
    __syncthreads();
    bf16x8 af[2], bfr[4];
#pragma unroll
    for (int m = 0; m < 2; ++m)
      af[m] = *reinterpret_cast<const bf16x8*>(&As[wm * 32 + m * 16 + lrow][lk]);
#pragma unroll
    for (int n = 0; n < 4; ++n)
      bfr[n] = *reinterpret_cast<const bf16x8*>(&Bs[wn * 64 + n * 16 + lrow][lk]);
#pragma unroll
    for (int m = 0; m < 2; ++m)
#pragma unroll
      for (int n = 0; n < 4; ++n)
        acc[m][n] = __builtin_amdgcn_mfma_f32_16x16x32_bf16(af[m], bfr[n], acc[m][n], 0, 0, 0);
    __syncthreads();
  }
  // epilogue: C/D layout col=lane&15, row=(lane>>4)*4+j; store sortable-u16
#pragma unroll
  for (int m = 0; m < 2; ++m) {
    int row0 = rb + wm * 32 + m * 16 + (lane >> 4) * 4;
#pragma unroll
    for (int n = 0; n < 4; ++n) {
      int col = wn * 64 + n * 16 + lrow;
#pragma unroll
      for (int j = 0; j < 4; ++j) {
        int r = row0 + j;
        if (r < N_NODES) H1[(size_t)r * NHID + col] = bf2sort(f2bf(acc[m][n][j]));
      }
    }
  }
}

// ======================= GEMM2 (MFMA): h2 = X1(bf16) @ W2 -> sortable-u16 =======================
// 128-row tile x 32 cols, K=128 (4 steps), 4 waves (each 32 rows x 32 cols).

__global__ __launch_bounds__(256) void gemm2_k(const uint_t* __restrict__ X1u,
                                               const float* __restrict__ W,
                                               ushort_t* __restrict__ H2s) {
  __shared__ ushort_t As[128][136];  // [row][k] +8 pad
  __shared__ ushort_t Bs[32][136];   // [col][k] (W2 transposed)
  int tid = threadIdx.x;
  int rb = blockIdx.x * 128;
  int lane = tid & 63, wid = tid >> 6;
  int lrow = lane & 15, lk = (lane >> 4) * 8;

#pragma unroll
  for (int j = 0; j < 8; ++j) {
    int f = tid + j * 256;   // uint4 index
    int row = f >> 4;
    int q = f & 15;
    int grow = rb + row;
    uint4 v = make_uint4(0, 0, 0, 0);
    if (grow < N_NODES)
      v = *reinterpret_cast<const uint4*>(X1u + (size_t)grow * 64 + q * 4);
    *reinterpret_cast<uint4*>(&As[row][q * 8]) = v;
  }
  {
    int bn = tid & 31, bq = tid >> 5;
    const float* gp = W + (size_t)(bq * 16) * NCLASS + bn;
    bf16x8 p0, p1;
#pragma unroll
    for (int j = 0; j < 8; ++j) p0[j] = (__bf16)gp[(size_t)j * NCLASS];
#pragma unroll
    for (int j = 0; j < 8; ++j) p1[j] = (__bf16)gp[(size_t)(8 + j) * NCLASS];
    *reinterpret_cast<bf16x8*>(&Bs[bn][bq * 16]) = p0;
    *reinterpret_cast<bf16x8*>(&Bs[bn][bq * 16 + 8]) = p1;
  }
  __syncthreads();

  f32x4 acc[2][2];
#pragma unroll
  for (int m = 0; m < 2; ++m)
#pragma unroll
    for (int n = 0; n < 2; ++n) acc[m][n] = (f32x4){0.f, 0.f, 0.f, 0.f};

#pragma unroll
  for (int ks = 0; ks < 4; ++ks) {
    bf16x8 af[2], bfr[2];
#pragma unroll
    for (int m = 0; m < 2; ++m)
      af[m] = *reinterpret_cast<const bf16x8*>(&As[wid * 32 + m * 16 + lrow][ks * 32 + lk]);
#pragma unroll
    for (int n = 0; n < 2; ++n)
      bfr[n] = *reinterpret_cast<const bf16x8*>(&Bs[n * 16 + lrow][ks * 32 + lk]);
#pragma unroll
    for (int m = 0; m < 2; ++m)
#pragma unroll
      for (int n = 0; n < 2; ++n)
        acc[m][n] = __builtin_amdgcn_mfma_f32_16x16x32_bf16(af[m], bfr[n], acc[m][n], 0, 0, 0);
  }
#pragma unroll
  for (int m = 0; m < 2; ++m) {
    int row0 = rb + wid * 32 + m * 16 + (lane >> 4) * 4;
#pragma unroll
    for (int n = 0; n < 2; ++n) {
      int col = n * 16 + lrow;
#pragma unroll
      for (int j = 0; j < 4; ++j) {
        int r = row0 + j;
        if (r < N_NODES) H2s[(size_t)r * NCLASS + col] = bf2sort(f2bf(acc[m][n][j]));
      }
    }
  }
}

// ======================= packed-u16 Batcher sort (2 features per reg) =======================

template <int NP>
__device__ __forceinline__ void pk_sort(u16x2 (&a)[NP]) {
#pragma unroll
  for (int p = 1; p < NP; p <<= 1) {
#pragma unroll
    for (int q = p; q >= 1; q >>= 1) {
#pragma unroll
      for (int j = q % p; j + q < NP; j += 2 * q) {
#pragma unroll
        for (int i = 0; i < q; ++i) {
          int lo = i + j, hi = i + j + q;
          if (hi < NP && (lo / (2 * p)) == (hi / (2 * p))) {
            u16x2 x = a[lo], y = a[hi];
            a[lo] = __builtin_elementwise_min(x, y);  // v_pk_min_u16
            a[hi] = __builtin_elementwise_max(x, y);  // v_pk_max_u16
          }
        }
      }
    }
  }
}

// ======================= Median layer 1 + bias + ReLU =======================
// ONE wave per node; lane t owns features {2t,2t+1} packed in one dword.

template <int KP>
__device__ __forceinline__ uint_t med1_path(const uint_t* __restrict__ H1p, int sreg,
                                            int k, int m, int t) {
  u16x2 a[KP];
#pragma unroll
  for (int e = 0; e < KP; ++e) {
    int s = __builtin_amdgcn_readlane(sreg, e);
    uint_t u = H1p[(size_t)s * 64 + t];
    uint_t pu = (e < k) ? u : 0xFFFFFFFFu;  // pad sorts to end
    union { uint_t u; u16x2 v; } c;
    c.u = pu;
    a[e] = c.v;
  }
  pk_sort<KP>(a);
  u16x2 med = a[0];
#pragma unroll
  for (int i = 1; i <= (KP - 1) / 2; ++i)
    if (i == m) med = a[i];  // wave-uniform m
  union { u16x2 v; uint_t u; } r;
  r.v = med;
  return r.u;
}

__global__ __launch_bounds__(256, 8) void med1_k(const ushort_t* __restrict__ H1,
                                                 const int* __restrict__ cur,
                                                 const ushort_t* __restrict__ adjw,
                                                 const float* __restrict__ b1,
                                                 uint_t* __restrict__ X1u) {
  int v = blockIdx.x * 4 + (threadIdx.x >> 6);
  int t = threadIdx.x & 63;
  int k = cur[v] + 1;
  if (k > STRIDE) k = STRIDE;
  int sreg = adjw[v * STRIDE + ((t < k) ? t : 0)];
  int m = (k - 1) >> 1;
  const uint_t* H1p = reinterpret_cast<const uint_t*>(H1);
  uint_t mu;
  if (k <= 16)      mu = med1_path<16>(H1p, sreg, k, m, t);
  else if (k <= 32) mu = med1_path<32>(H1p, sreg, k, m, t);
  else              mu = med1_path<48>(H1p, sreg, k, m, t);
  ushort_t s0 = (ushort_t)(mu & 0xFFFF), s1 = (ushort_t)(mu >> 16);
  float2 bb = *reinterpret_cast<const float2*>(b1 + 2 * t);
  float f0 = fmaxf(bf2f(sort2bf(s0)) + bb.x, 0.f);
  float f1 = fmaxf(bf2f(sort2bf(s1)) + bb.y, 0.f);
  X1u[(size_t)v * 64 + t] = (uint_t)f2bf(f0) | ((uint_t)f2bf(f1) << 16);
}

// ============ Median layer 2 (packed-u16) + bias + fused log_softmax ============
// 4 nodes per wave: 16-lane group per node, lane l owns classes {2l, 2l+1}.

template <int KP>
__device__ __forceinline__ uint_t med2_path(const uint_t* __restrict__ H2p,
                                            int s0, int s1, int s2,
                                            int k, int m, int g, int l) {
  u16x2 a[KP];
#pragma unroll
  for (int e = 0; e < KP; ++e) {
    int sr = (e < 16) ? s0 : ((e < 32) ? s1 : s2);
    int srcid = __shfl(sr, g * 16 + (e & 15), 64);  // group broadcast
    uint_t u = H2p[(size_t)srcid * 16 + l];
    uint_t pu = (e < k) ? u : 0xFFFFFFFFu;
    union { uint_t u; u16x2 v; } c;
    c.u = pu;
    a[e] = c.v;
  }
  pk_sort<KP>(a);
  u16x2 med = a[0];
#pragma unroll
  for (int i = 1; i <= (KP - 1) / 2; ++i)
    if (i == m) med = a[i];  // m uniform within group
  union { u16x2 v; uint_t u; } r;
  r.v = med;
  return r.u;
}

__global__ __launch_bounds__(256, 8) void med2_k(const ushort_t* __restrict__ H2,
                                                 const int* __restrict__ cur,
                                                 const ushort_t* __restrict__ adjw,
                                                 const float* __restrict__ b2,
                                                 float* __restrict__ OUT) {
  int w = threadIdx.x >> 6;
  int t = threadIdx.x & 63;
  int l = t & 15, g = t >> 4;  // group g in [0,4), lane l in group
  int vh = (blockIdx.x * 4 + w) * 4 + g;
  int k = cur[vh] + 1;
  if (k > STRIDE) k = STRIDE;
  int m = (k - 1) >> 1;
  // three adjacency slots per lane (u16 loads), clamped to valid range
  int base = vh * STRIDE;
  int s0 = adjw[base + ((l < k) ? l : 0)];
  int s1 = adjw[base + ((16 + l < k) ? 16 + l : 0)];
  int s2 = adjw[base + ((32 + l < k) ? 32 + l : 0)];
  // wave-wide kmax (k uniform within each 16-lane group)
  int kmax = max(k, __shfl_xor(k, 16, 64));
  kmax = max(kmax, __shfl_xor(kmax, 32, 64));
  const uint_t* H2p = reinterpret_cast<const uint_t*>(H2);
  uint_t mu;
  if (kmax <= 16)      mu = med2_path<16>(H2p, s0, s1, s2, k, m, g, l);
  else if (kmax <= 32) mu = med2_path<32>(H2p, s0, s1, s2, k, m, g, l);
  else                 mu = med2_path<48>(H2p, s0, s1, s2, k, m, g, l);
  ushort_t u0 = (ushort_t)(mu & 0xFFFF), u1 = (ushort_t)(mu >> 16);
  float2 bb = *reinterpret_cast<const float2*>(b2 + 2 * l);
  float f0 = bf2f(sort2bf(u0)) + bb.x;
  float f1 = bf2f(sort2bf(u1)) + bb.y;
  // log_softmax over the 32 classes held by this 16-lane group
  float mx = fmaxf(f0, f1);
#pragma unroll
  for (int s = 8; s; s >>= 1) mx = fmaxf(mx, __shfl_xor(mx, s, 16));
  float sum = expf(f0 - mx) + expf(f1 - mx);
#pragma unroll
  for (int s = 8; s; s >>= 1) sum += __shfl_xor(sum, s, 16);
  float lg = logf(sum);
  float2 res = make_float2(f0 - mx - lg, f1 - mx - lg);
  *reinterpret_cast<float2*>(&OUT[(size_t)vh * NCLASS + 2 * l]) = res;
}

// ======================= launcher =======================

extern "C" void kernel_launch(void* const* d_in, const int* in_sizes, int n_in,
                              void* d_out, int out_size, void* d_ws, size_t ws_size,
                              hipStream_t stream) {
  const float* X = (const float*)d_in[0];
  const int* src = (const int*)d_in[1];
  const int* dst = src + N_EDGES;
  const float* W1 = (const float*)d_in[2];
  const float* b1 = (const float*)d_in[3];
  const float* W2 = (const float*)d_in[4];
  const float* b2 = (const float*)d_in[5];
  float* OUT = (float*)d_out;

  char* w = (char*)d_ws;
  size_t o = 0;
  auto take = [&](size_t bytes) {
    void* p = w + o;
    o += (bytes + 255) & ~(size_t)255;
    return p;
  };
  int* cur = (int*)take(N_NODES * sizeof(int));
  ushort_t* adjw = (ushort_t*)take((size_t)N_NODES * STRIDE * sizeof(ushort_t));
  ushort_t* h1 = (ushort_t*)take((size_t)N_NODES * NHID * sizeof(ushort_t));
  uint_t* x1 = (uint_t*)take((size_t)N_NODES * 64 * sizeof(uint_t));
  ushort_t* h2 = (ushort_t*)take((size_t)N_NODES * NCLASS * sizeof(ushort_t));
  (void)ws_size;

  hipMemsetAsync(cur, 0, N_NODES * sizeof(int), stream);
  int scatter_blocks = (N_EDGES + N_NODES + 255) / 256;
  scatter_k<<<scatter_blocks, 256, 0, stream>>>(src, dst, cur, adjw);
  gemm1_k<<<G1B, 256, 0, stream>>>(X, W1, h1);
  med1_k<<<N_NODES / 4, 256, 0, stream>>>(h1, cur, adjw, b1, x1);
  gemm2_k<<<(N_NODES + 127) / 128, 256, 0, stream>>>(x1, W2, h2);
  med2_k<<<N_NODES / 16, 256, 0, stream>>>(h2, cur, adjw, b2, OUT);
}

// Round 4
// 112.324 us; speedup vs baseline: 1.2712x; 1.2712x over previous
//
#include <hip/hip_runtime.h>
#include <hip/hip_bf16.h>
#include <math.h>

#define N_NODES 50000
#define N_EDGES 800000
#define NFEAT 256
#define NHID 128
#define NCLASS 32
#define STRIDE 48  // padded CSR row stride; slot 0 = self loop
#define G1B 782    // ceil(N_NODES/64) gemm1 blocks

#define NBKT 196   // destination buckets: d >> 8 (256 nodes/bucket)
#define CAPB 6144  // per-bucket edge capacity (mean 4096, sigma 64 -> 32 sigma headroom)
#define TILE 2048  // edges per bin_k block
#define NTILE ((N_EDGES + TILE - 1) / TILE)  // 391

#define INFF __builtin_inff()

typedef unsigned short ushort_t;
typedef unsigned int uint_t;
typedef __bf16 bf16x8 __attribute__((ext_vector_type(8)));
typedef float f32x4 __attribute__((ext_vector_type(4)));
typedef unsigned short u16x2 __attribute__((ext_vector_type(2)));

__device__ __forceinline__ float bf2f(ushort_t u) {
  union { unsigned int i; float f; } c;
  c.i = ((unsigned int)u) << 16;
  return c.f;
}
__device__ __forceinline__ ushort_t f2bf(float f) {
  unsigned int x = __float_as_uint(f);
  unsigned int r = (x + 0x7fff + ((x >> 16) & 1)) >> 16;  // RNE
  return (ushort_t)r;
}
// monotone bf16-bits -> sortable-u16 (unsigned order == float order)
__device__ __forceinline__ ushort_t bf2sort(ushort_t b) {
  return b ^ ((b & 0x8000) ? 0xFFFFu : 0x8000u);
}
__device__ __forceinline__ ushort_t sort2bf(ushort_t s) {
  return s ^ ((s & 0x8000) ? 0x8000u : 0xFFFFu);
}

// ======================= bin_k: tile-local counting sort of edges by dst bucket =======================
// Replaces per-edge global atomic+2B-store (1 fabric txn each) with LDS binning +
// coalesced run writes. Global atomics: 1 per (block,bucket) = ~76K instead of 800K.

__global__ __launch_bounds__(256) void bin_k(const int* __restrict__ src,
                                             const int* __restrict__ dst,
                                             int* __restrict__ gcnt,
                                             uint_t* __restrict__ buf) {
  __shared__ int hist[NBKT];
  __shared__ int lbase[NBKT];
  __shared__ int gbase[NBKT];
  __shared__ int lcur[NBKT];
  __shared__ int scanbuf[256];
  __shared__ uint_t val[TILE];
  __shared__ unsigned char bkt[TILE];
  int tid = threadIdx.x;
  int e0 = blockIdx.x * TILE;

  for (int b = tid; b < NBKT; b += 256) hist[b] = 0;
  __syncthreads();

  // pass 1: load edges, filter self loops, histogram buckets
  int myb[TILE / 256];
  uint_t myv[TILE / 256];
#pragma unroll
  for (int j = 0; j < TILE / 256; ++j) {
    int i = e0 + j * 256 + tid;
    int b = -1;
    uint_t v = 0;
    if (i < N_EDGES) {
      int s = src[i], d = dst[i];
      if (s != d) {
        b = d >> 8;
        v = ((uint_t)(d & 255) << 16) | (uint_t)s;
        atomicAdd(&hist[b], 1);
      }
    }
    myb[j] = b;
    myv[j] = v;
  }
  __syncthreads();

  // reserve global runs + inclusive scan of hist (Hillis-Steele over 256 slots)
  if (tid < NBKT) gbase[tid] = atomicAdd(&gcnt[tid], hist[tid]);
  scanbuf[tid] = (tid < NBKT) ? hist[tid] : 0;
  __syncthreads();
  for (int off = 1; off < 256; off <<= 1) {
    int v = (tid >= off) ? scanbuf[tid - off] : 0;
    __syncthreads();
    scanbuf[tid] += v;
    __syncthreads();
  }
  if (tid < NBKT) {
    lbase[tid] = scanbuf[tid] - hist[tid];  // exclusive
    lcur[tid] = 0;
  }
  __syncthreads();

  // pass 2: scatter into LDS at bucket-sorted local slots
#pragma unroll
  for (int j = 0; j < TILE / 256; ++j) {
    int b = myb[j];
    if (b >= 0) {
      int sl = lbase[b] + atomicAdd(&lcur[b], 1);
      val[sl] = myv[j];
      bkt[sl] = (unsigned char)b;
    }
  }
  __syncthreads();

  // write out: consecutive slots -> consecutive global addresses per bucket run
  int ntot = scanbuf[255];
  for (int sl = tid; sl < ntot; sl += 256) {
    int b = bkt[sl];
    int off = gbase[b] + (sl - lbase[b]);
    if (off < CAPB) buf[(size_t)b * CAPB + off] = val[sl];
  }
}

// ======================= build_k: per-bucket CSR row construction in LDS =======================
// One block per 256-node bucket. LDS atomics for slot counters (no fabric txns),
// full-line uint4 writes of adjw rows + coalesced cur writes.

__global__ __launch_bounds__(256) void build_k(const int* __restrict__ gcnt,
                                               const uint_t* __restrict__ buf,
                                               int* __restrict__ cur,
                                               ushort_t* __restrict__ adjw) {
  __shared__ __attribute__((aligned(16))) ushort_t rows[256 * STRIDE];
  __shared__ int cnt[256];
  int b = blockIdx.x, tid = threadIdx.x;
  int v0 = b << 8;
  int nv = N_NODES - v0;
  if (nv > 256) nv = 256;
  cnt[tid] = 1;  // slot 0 = self loop
  if (tid < nv) rows[tid * STRIDE] = (ushort_t)(v0 + tid);
  __syncthreads();

  int n = gcnt[b];
  if (n > CAPB) n = CAPB;
  for (int i = tid; i < n; i += 256) {
    uint_t e = buf[(size_t)b * CAPB + i];
    int s = e & 0xFFFF;
    int doff = e >> 16;
    int p = atomicAdd(&cnt[doff], 1);
    if (p < STRIDE) rows[doff * STRIDE + p] = (ushort_t)s;
  }
  __syncthreads();

  int nq = nv * 6;  // uint4 per node: 48*2/16 = 6
  uint4* gout = reinterpret_cast<uint4*>(adjw + (size_t)v0 * STRIDE);
  const uint4* ls = reinterpret_cast<const uint4*>(rows);
  for (int i = tid; i < nq; i += 256) gout[i] = ls[i];
  if (tid < nv) cur[v0 + tid] = cnt[tid] - 1;
}

// ======================= GEMM1 (MFMA): h1 = X @ W1 -> sortable-u16 =======================
// 64x128 tile, BK=32, 4 waves (32x64 each).

__global__ __launch_bounds__(256) void gemm1_k(const float* __restrict__ X,
                                               const float* __restrict__ W,
                                               ushort_t* __restrict__ H1) {
  __shared__ ushort_t As[64][40];   // [row][k], +8 pad
  __shared__ ushort_t Bs[128][40];  // [col][k] (W1 transposed)
  int bid = blockIdx.x;
  int tid = threadIdx.x;

  int rb = bid * 64;
  int lane = tid & 63, wid = tid >> 6;
  int wm = wid >> 1, wn = wid & 1;   // wm: 32-row half, wn: 64-col half
  int lrow = lane & 15, lk = (lane >> 4) * 8;
  int arow = tid >> 2, akq = (tid & 3) * 8;  // A staging: 64 rows x 4 chunks of 8
  int bn = tid & 127, bkh = tid >> 7;        // B staging: col, 16-wide k-half

  f32x4 acc[2][4];
#pragma unroll
  for (int m = 0; m < 2; ++m)
#pragma unroll
    for (int n = 0; n < 4; ++n) acc[m][n] = (f32x4){0.f, 0.f, 0.f, 0.f};

  for (int kc = 0; kc < NFEAT; kc += 32) {
    // stage A: 64 rows x 32 k, f32 -> bf16 (8 elems per thread)
    {
      int grow = rb + arow;
      bf16x8 p;
      if (grow < N_NODES) {
        const float* gp = X + (size_t)grow * NFEAT + kc + akq;
        float4 v0 = *reinterpret_cast<const float4*>(gp);
        float4 v1 = *reinterpret_cast<const float4*>(gp + 4);
        p[0] = (__bf16)v0.x; p[1] = (__bf16)v0.y; p[2] = (__bf16)v0.z; p[3] = (__bf16)v0.w;
        p[4] = (__bf16)v1.x; p[5] = (__bf16)v1.y; p[6] = (__bf16)v1.z; p[7] = (__bf16)v1.w;
      } else {
        p = (bf16x8)(__bf16)0.f;
      }
      *reinterpret_cast<bf16x8*>(&As[arow][akq]) = p;
    }
    // stage B transposed: Bs[n][k] <- W[kc+k][n]
    {
      const float* gp = W + (size_t)(kc + bkh * 16) * NHID + bn;
      bf16x8 p0, p1;
#pragma unroll
      for (int j = 0; j < 8; ++j) p0[j] = (__bf16)gp[(size_t)j * NHID];
#pragma unroll
      for (int j = 0; j < 8; ++j) p1[j] = (__bf16)gp[(size_t)(8 + j) * NHID];
      *reinterpret_cast<bf16x8*>(&Bs[bn][bkh * 16]) = p0;
      *reinterpret_cast<bf16x8*>(&Bs[bn][bkh * 16 + 8]) = p1;
    }
    __syncthreads();
    bf16x8 af[2], bfr[4];
#pragma unroll
    for (int m = 0; m < 2; ++m)
      af[m] = *reinterpret_cast<const bf16x8*>(&As[wm * 32 + m * 16 + lrow][lk]);
#pragma unroll
    for (int n = 0; n < 4; ++n)
      bfr[n] = *reinterpret_cast<const bf16x8*>(&Bs[wn * 64 + n * 16 + lrow][lk]);
#pragma unroll
    for (int m = 0; m < 2; ++m)
#pragma unroll
      for (int n = 0; n < 4; ++n)
        acc[m][n] = __builtin_amdgcn_mfma_f32_16x16x32_bf16(af[m], bfr[n], acc[m][n], 0, 0, 0);
    __syncthreads();
  }
  // epilogue: C/D layout col=lane&15, row=(lane>>4)*4+j; store sortable-u16
#pragma unroll
  for (int m = 0; m < 2; ++m) {
    int row0 = rb + wm * 32 + m * 16 + (lane >> 4) * 4;
#pragma unroll
    for (int n = 0; n < 4; ++n) {
      int col = wn * 64 + n * 16 + lrow;
#pragma unroll
      for (int j = 0; j < 4; ++j) {
        int r = row0 + j;
        if (r < N_NODES) H1[(size_t)r * NHID + col] = bf2sort(f2bf(acc[m][n][j]));
      }
    }
  }
}

// ======================= GEMM2 (MFMA): h2 = X1(bf16) @ W2 -> sortable-u16 =======================
// 128-row tile x 32 cols, K=128 (4 steps), 4 waves (each 32 rows x 32 cols).

__global__ __launch_bounds__(256) void gemm2_k(const uint_t* __restrict__ X1u,
                                               const float* __restrict__ W,
                                               ushort_t* __restrict__ H2s) {
  __shared__ ushort_t As[128][136];  // [row][k] +8 pad
  __shared__ ushort_t Bs[32][136];   // [col][k] (W2 transposed)
  int tid = threadIdx.x;
  int rb = blockIdx.x * 128;
  int lane = tid & 63, wid = tid >> 6;
  int lrow = lane & 15, lk = (lane >> 4) * 8;

#pragma unroll
  for (int j = 0; j < 8; ++j) {
    int f = tid + j * 256;   // uint4 index
    int row = f >> 4;
    int q = f & 15;
    int grow = rb + row;
    uint4 v = make_uint4(0, 0, 0, 0);
    if (grow < N_NODES)
      v = *reinterpret_cast<const uint4*>(X1u + (size_t)grow * 64 + q * 4);
    *reinterpret_cast<uint4*>(&As[row][q * 8]) = v;
  }
  {
    int bn = tid & 31, bq = tid >> 5;
    const float* gp = W + (size_t)(bq * 16) * NCLASS + bn;
    bf16x8 p0, p1;
#pragma unroll
    for (int j = 0; j < 8; ++j) p0[j] = (__bf16)gp[(size_t)j * NCLASS];
#pragma unroll
    for (int j = 0; j < 8; ++j) p1[j] = (__bf16)gp[(size_t)(8 + j) * NCLASS];
    *reinterpret_cast<bf16x8*>(&Bs[bn][bq * 16]) = p0;
    *reinterpret_cast<bf16x8*>(&Bs[bn][bq * 16 + 8]) = p1;
  }
  __syncthreads();

  f32x4 acc[2][2];
#pragma unroll
  for (int m = 0; m < 2; ++m)
#pragma unroll
    for (int n = 0; n < 2; ++n) acc[m][n] = (f32x4){0.f, 0.f, 0.f, 0.f};

#pragma unroll
  for (int ks = 0; ks < 4; ++ks) {
    bf16x8 af[2], bfr[2];
#pragma unroll
    for (int m = 0; m < 2; ++m)
      af[m] = *reinterpret_cast<const bf16x8*>(&As[wid * 32 + m * 16 + lrow][ks * 32 + lk]);
#pragma unroll
    for (int n = 0; n < 2; ++n)
      bfr[n] = *reinterpret_cast<const bf16x8*>(&Bs[n * 16 + lrow][ks * 32 + lk]);
#pragma unroll
    for (int m = 0; m < 2; ++m)
#pragma unroll
      for (int n = 0; n < 2; ++n)
        acc[m][n] = __builtin_amdgcn_mfma_f32_16x16x32_bf16(af[m], bfr[n], acc[m][n], 0, 0, 0);
  }
#pragma unroll
  for (int m = 0; m < 2; ++m) {
    int row0 = rb + wid * 32 + m * 16 + (lane >> 4) * 4;
#pragma unroll
    for (int n = 0; n < 2; ++n) {
      int col = n * 16 + lrow;
#pragma unroll
      for (int j = 0; j < 4; ++j) {
        int r = row0 + j;
        if (r < N_NODES) H2s[(size_t)r * NCLASS + col] = bf2sort(f2bf(acc[m][n][j]));
      }
    }
  }
}

// ======================= packed-u16 Batcher sort (2 features per reg) =======================

template <int NP>
__device__ __forceinline__ void pk_sort(u16x2 (&a)[NP]) {
#pragma unroll
  for (int p = 1; p < NP; p <<= 1) {
#pragma unroll
    for (int q = p; q >= 1; q >>= 1) {
#pragma unroll
      for (int j = q % p; j + q < NP; j += 2 * q) {
#pragma unroll
        for (int i = 0; i < q; ++i) {
          int lo = i + j, hi = i + j + q;
          if (hi < NP && (lo / (2 * p)) == (hi / (2 * p))) {
            u16x2 x = a[lo], y = a[hi];
            a[lo] = __builtin_elementwise_min(x, y);  // v_pk_min_u16
            a[hi] = __builtin_elementwise_max(x, y);  // v_pk_max_u16
          }
        }
      }
    }
  }
}

// ======================= Median layer 1 + bias + ReLU =======================
// ONE wave per node; lane t owns features {2t,2t+1} packed in one dword.

template <int KP>
__device__ __forceinline__ uint_t med1_path(const uint_t* __restrict__ H1p, int sreg,
                                            int k, int m, int t) {
  u16x2 a[KP];
#pragma unroll
  for (int e = 0; e < KP; ++e) {
    int s = __builtin_amdgcn_readlane(sreg, e);
    uint_t u = H1p[(size_t)s * 64 + t];
    uint_t pu = (e < k) ? u : 0xFFFFFFFFu;  // pad sorts to end
    union { uint_t u; u16x2 v; } c;
    c.u = pu;
    a[e] = c.v;
  }
  pk_sort<KP>(a);
  u16x2 med = a[0];
#pragma unroll
  for (int i = 1; i <= (KP - 1) / 2; ++i)
    if (i == m) med = a[i];  // wave-uniform m
  union { u16x2 v; uint_t u; } r;
  r.v = med;
  return r.u;
}

__global__ __launch_bounds__(256, 8) void med1_k(const ushort_t* __restrict__ H1,
                                                 const int* __restrict__ cur,
                                                 const ushort_t* __restrict__ adjw,
                                                 const float* __restrict__ b1,
                                                 uint_t* __restrict__ X1u) {
  int v = blockIdx.x * 4 + (threadIdx.x >> 6);
  int t = threadIdx.x & 63;
  int k = cur[v] + 1;
  if (k > STRIDE) k = STRIDE;
  int sreg = adjw[v * STRIDE + ((t < k) ? t : 0)];
  int m = (k - 1) >> 1;
  const uint_t* H1p = reinterpret_cast<const uint_t*>(H1);
  uint_t mu;
  if (k <= 16)      mu = med1_path<16>(H1p, sreg, k, m, t);
  else if (k <= 32) mu = med1_path<32>(H1p, sreg, k, m, t);
  else              mu = med1_path<48>(H1p, sreg, k, m, t);
  ushort_t s0 = (ushort_t)(mu & 0xFFFF), s1 = (ushort_t)(mu >> 16);
  float2 bb = *reinterpret_cast<const float2*>(b1 + 2 * t);
  float f0 = fmaxf(bf2f(sort2bf(s0)) + bb.x, 0.f);
  float f1 = fmaxf(bf2f(sort2bf(s1)) + bb.y, 0.f);
  X1u[(size_t)v * 64 + t] = (uint_t)f2bf(f0) | ((uint_t)f2bf(f1) << 16);
}

// ============ Median layer 2 (packed-u16) + bias + fused log_softmax ============
// 4 nodes per wave: 16-lane group per node, lane l owns classes {2l, 2l+1}.

template <int KP>
__device__ __forceinline__ uint_t med2_path(const uint_t* __restrict__ H2p,
                                            int s0, int s1, int s2,
                                            int k, int m, int g, int l) {
  u16x2 a[KP];
#pragma unroll
  for (int e = 0; e < KP; ++e) {
    int sr = (e < 16) ? s0 : ((e < 32) ? s1 : s2);
    int srcid = __shfl(sr, g * 16 + (e & 15), 64);  // group broadcast
    uint_t u = H2p[(size_t)srcid * 16 + l];
    uint_t pu = (e < k) ? u : 0xFFFFFFFFu;
    union { uint_t u; u16x2 v; } c;
    c.u = pu;
    a[e] = c.v;
  }
  pk_sort<KP>(a);
  u16x2 med = a[0];
#pragma unroll
  for (int i = 1; i <= (KP - 1) / 2; ++i)
    if (i == m) med = a[i];  // m uniform within group
  union { u16x2 v; uint_t u; } r;
  r.v = med;
  return r.u;
}

__global__ __launch_bounds__(256, 8) void med2_k(const ushort_t* __restrict__ H2,
                                                 const int* __restrict__ cur,
                                                 const ushort_t* __restrict__ adjw,
                                                 const float* __restrict__ b2,
                                                 float* __restrict__ OUT) {
  int w = threadIdx.x >> 6;
  int t = threadIdx.x & 63;
  int l = t & 15, g = t >> 4;  // group g in [0,4), lane l in group
  int vh = (blockIdx.x * 4 + w) * 4 + g;
  int k = cur[vh] + 1;
  if (k > STRIDE) k = STRIDE;
  int m = (k - 1) >> 1;
  // three adjacency slots per lane (u16 loads), clamped to valid range
  int base = vh * STRIDE;
  int s0 = adjw[base + ((l < k) ? l : 0)];
  int s1 = adjw[base + ((16 + l < k) ? 16 + l : 0)];
  int s2 = adjw[base + ((32 + l < k) ? 32 + l : 0)];
  // wave-wide kmax (k uniform within each 16-lane group)
  int kmax = max(k, __shfl_xor(k, 16, 64));
  kmax = max(kmax, __shfl_xor(kmax, 32, 64));
  const uint_t* H2p = reinterpret_cast<const uint_t*>(H2);
  uint_t mu;
  if (kmax <= 16)      mu = med2_path<16>(H2p, s0, s1, s2, k, m, g, l);
  else if (kmax <= 32) mu = med2_path<32>(H2p, s0, s1, s2, k, m, g, l);
  else                 mu = med2_path<48>(H2p, s0, s1, s2, k, m, g, l);
  ushort_t u0 = (ushort_t)(mu & 0xFFFF), u1 = (ushort_t)(mu >> 16);
  float2 bb = *reinterpret_cast<const float2*>(b2 + 2 * l);
  float f0 = bf2f(sort2bf(u0)) + bb.x;
  float f1 = bf2f(sort2bf(u1)) + bb.y;
  // log_softmax over the 32 classes held by this 16-lane group
  float mx = fmaxf(f0, f1);
#pragma unroll
  for (int s = 8; s; s >>= 1) mx = fmaxf(mx, __shfl_xor(mx, s, 16));
  float sum = expf(f0 - mx) + expf(f1 - mx);
#pragma unroll
  for (int s = 8; s; s >>= 1) sum += __shfl_xor(sum, s, 16);
  float lg = logf(sum);
  float2 res = make_float2(f0 - mx - lg, f1 - mx - lg);
  *reinterpret_cast<float2*>(&OUT[(size_t)vh * NCLASS + 2 * l]) = res;
}

// ======================= launcher =======================

extern "C" void kernel_launch(void* const* d_in, const int* in_sizes, int n_in,
                              void* d_out, int out_size, void* d_ws, size_t ws_size,
                              hipStream_t stream) {
  const float* X = (const float*)d_in[0];
  const int* src = (const int*)d_in[1];
  const int* dst = src + N_EDGES;
  const float* W1 = (const float*)d_in[2];
  const float* b1 = (const float*)d_in[3];
  const float* W2 = (const float*)d_in[4];
  const float* b2 = (const float*)d_in[5];
  float* OUT = (float*)d_out;

  char* w = (char*)d_ws;
  size_t o = 0;
  auto take = [&](size_t bytes) {
    void* p = w + o;
    o += (bytes + 255) & ~(size_t)255;
    return p;
  };
  int* cur = (int*)take(N_NODES * sizeof(int));
  ushort_t* adjw = (ushort_t*)take((size_t)N_NODES * STRIDE * sizeof(ushort_t));
  ushort_t* h1 = (ushort_t*)take((size_t)N_NODES * NHID * sizeof(ushort_t));
  uint_t* x1 = (uint_t*)take((size_t)N_NODES * 64 * sizeof(uint_t));
  ushort_t* h2 = (ushort_t*)take((size_t)N_NODES * NCLASS * sizeof(ushort_t));
  int* gcnt = (int*)take(256 * sizeof(int));
  uint_t* buf = (uint_t*)take((size_t)NBKT * CAPB * sizeof(uint_t));
  (void)ws_size;

  hipMemsetAsync(gcnt, 0, 256 * sizeof(int), stream);
  bin_k<<<NTILE, 256, 0, stream>>>(src, dst, gcnt, buf);
  build_k<<<NBKT, 256, 0, stream>>>(gcnt, buf, cur, adjw);
  gemm1_k<<<G1B, 256, 0, stream>>>(X, W1, h1);
  med1_k<<<N_NODES / 4, 256, 0, stream>>>(h1, cur, adjw, b1, x1);
  gemm2_k<<<(N_NODES + 127) / 128, 256, 0, stream>>>(x1, W2, h2);
  med2_k<<<N_NODES / 16, 256, 0, stream>>>(h2, cur, adjw, b2, OUT);
}

// Round 5
// 99.835 us; speedup vs baseline: 1.4302x; 1.1251x over previous
//
#include <hip/hip_runtime.h>
#include <hip/hip_bf16.h>
#include <math.h>

#define N_NODES 50000
#define N_EDGES 800000
#define NFEAT 256
#define NHID 128
#define NCLASS 32
#define STRIDE 48  // padded CSR row stride; slot 0 = self loop
#define G1B 782    // ceil(N_NODES/64) gemm1 blocks

#define NBKT 196   // destination buckets: d >> 8 (256 nodes/bucket)
#define CAPB 6144  // per-bucket edge capacity (mean 4096, sigma 64 -> 32 sigma headroom)
#define TILE 2048  // edges per bin block
#define NTILE ((N_EDGES + TILE - 1) / TILE)  // 391

#define INFF __builtin_inff()

typedef unsigned short ushort_t;
typedef unsigned int uint_t;
typedef __bf16 bf16x8 __attribute__((ext_vector_type(8)));
typedef float f32x4 __attribute__((ext_vector_type(4)));
typedef unsigned short u16x2 __attribute__((ext_vector_type(2)));

__device__ __forceinline__ float bf2f(ushort_t u) {
  union { unsigned int i; float f; } c;
  c.i = ((unsigned int)u) << 16;
  return c.f;
}
__device__ __forceinline__ ushort_t f2bf(float f) {
  unsigned int x = __float_as_uint(f);
  unsigned int r = (x + 0x7fff + ((x >> 16) & 1)) >> 16;  // RNE
  return (ushort_t)r;
}
// monotone bf16-bits -> sortable-u16 (unsigned order == float order)
__device__ __forceinline__ ushort_t bf2sort(ushort_t b) {
  return b ^ ((b & 0x8000) ? 0xFFFFu : 0x8000u);
}
__device__ __forceinline__ ushort_t sort2bf(ushort_t s) {
  return s ^ ((s & 0x8000) ? 0x8000u : 0xFFFFu);
}

// ============ fused pre_k: blocks [0,G1B) = GEMM1 (MFMA), rest = edge binning ============
// GEMM1 and binning are independent (GEMM1 reads X/W1; binning reads edges), so they
// share one dispatch and overlap: bin work hides behind GEMM1's staging latency.
// LDS is a manual union (gemm needs 15360 B, bin needs 14400 B).

__global__ __launch_bounds__(256) void pre_k(const float* __restrict__ X,
                                             const float* __restrict__ W,
                                             ushort_t* __restrict__ H1,
                                             const int* __restrict__ src,
                                             const int* __restrict__ dst,
                                             int* __restrict__ gcnt,
                                             uint_t* __restrict__ buf) {
  __shared__ __attribute__((aligned(16))) char smem[15360];
  int bid = blockIdx.x;
  int tid = threadIdx.x;

  if (bid >= G1B) {
    // ---------------- bin: tile-local counting sort of edges by dst bucket ----------------
    // Replaces per-edge global atomic+2B-store (1 fabric txn each) with LDS binning +
    // coalesced run writes. Global atomics: 1 per (block,bucket) = ~76K total.
    uint_t* val = reinterpret_cast<uint_t*>(smem);                    // 8192 B
    int* scanbuf = reinterpret_cast<int*>(smem + 8192);               // 1024 B
    int* hist = reinterpret_cast<int*>(smem + 9216);                  // 784 B
    int* lbase = reinterpret_cast<int*>(smem + 10000);                // 784 B
    int* gbase = reinterpret_cast<int*>(smem + 10784);                // 784 B
    int* lcur = reinterpret_cast<int*>(smem + 11568);                 // 784 B
    unsigned char* bkt = reinterpret_cast<unsigned char*>(smem + 12352);  // 2048 B

    int e0 = (bid - G1B) * TILE;
    for (int b = tid; b < NBKT; b += 256) hist[b] = 0;
    __syncthreads();

    // pass 1: load edges, filter self loops, histogram buckets
    int myb[TILE / 256];
    uint_t myv[TILE / 256];
#pragma unroll
    for (int j = 0; j < TILE / 256; ++j) {
      int i = e0 + j * 256 + tid;
      int b = -1;
      uint_t v = 0;
      if (i < N_EDGES) {
        int s = src[i], d = dst[i];
        if (s != d) {
          b = d >> 8;
          v = ((uint_t)(d & 255) << 16) | (uint_t)s;
          atomicAdd(&hist[b], 1);
        }
      }
      myb[j] = b;
      myv[j] = v;
    }
    __syncthreads();

    // reserve global runs + inclusive scan of hist (Hillis-Steele over 256 slots)
    if (tid < NBKT) gbase[tid] = atomicAdd(&gcnt[tid], hist[tid]);
    scanbuf[tid] = (tid < NBKT) ? hist[tid] : 0;
    __syncthreads();
    for (int off = 1; off < 256; off <<= 1) {
      int v = (tid >= off) ? scanbuf[tid - off] : 0;
      __syncthreads();
      scanbuf[tid] += v;
      __syncthreads();
    }
    if (tid < NBKT) {
      lbase[tid] = scanbuf[tid] - hist[tid];  // exclusive
      lcur[tid] = 0;
    }
    __syncthreads();

    // pass 2: scatter into LDS at bucket-sorted local slots
#pragma unroll
    for (int j = 0; j < TILE / 256; ++j) {
      int b = myb[j];
      if (b >= 0) {
        int sl = lbase[b] + atomicAdd(&lcur[b], 1);
        val[sl] = myv[j];
        bkt[sl] = (unsigned char)b;
      }
    }
    __syncthreads();

    // write out: consecutive slots -> consecutive global addresses per bucket run
    int ntot = scanbuf[255];
    for (int sl = tid; sl < ntot; sl += 256) {
      int b = bkt[sl];
      int off = gbase[b] + (sl - lbase[b]);
      if (off < CAPB) buf[(size_t)b * CAPB + off] = val[sl];
    }
    return;
  }

  // ---------------- gemm1 (MFMA): h1 = X @ W1 -> sortable-u16 ----------------
  // 64x128 tile, BK=32, 4 waves (32x64 each).
  ushort_t (*As)[40] = reinterpret_cast<ushort_t(*)[40]>(smem);          // [64][40]
  ushort_t (*Bs)[40] = reinterpret_cast<ushort_t(*)[40]>(smem + 5120);   // [128][40]

  int rb = bid * 64;
  int lane = tid & 63, wid = tid >> 6;
  int wm = wid >> 1, wn = wid & 1;   // wm: 32-row half, wn: 64-col half
  int lrow = lane & 15, lk = (lane >> 4) * 8;
  int arow = tid >> 2, akq = (tid & 3) * 8;  // A staging: 64 rows x 4 chunks of 8
  int bn = tid & 127, bkh = tid >> 7;        // B staging: col, 16-wide k-half

  f32x4 acc[2][4];
#pragma unroll
  for (int m = 0; m < 2; ++m)
#pragma unroll
    for (int n = 0; n < 4; ++n) acc[m][n] = (f32x4){0.f, 0.f, 0.f, 0.f};

  for (int kc = 0; kc < NFEAT; kc += 32) {
    // stage A: 64 rows x 32 k, f32 -> bf16 (8 elems per thread)
    {
      int grow = rb + arow;
      bf16x8 p;
      if (grow < N_NODES) {
        const float* gp = X + (size_t)grow * NFEAT + kc + akq;
        float4 v0 = *reinterpret_cast<const float4*>(gp);
        float4 v1 = *reinterpret_cast<const float4*>(gp + 4);
        p[0] = (__bf16)v0.x; p[1] = (__bf16)v0.y; p[2] = (__bf16)v0.z; p[3] = (__bf16)v0.w;
        p[4] = (__bf16)v1.x; p[5] = (__bf16)v1.y; p[6] = (__bf16)v1.z; p[7] = (__bf16)v1.w;
      } else {
        p = (bf16x8)(__bf16)0.f;
      }
      *reinterpret_cast<bf16x8*>(&As[arow][akq]) = p;
    }
    // stage B transposed: Bs[n][k] <- W[kc+k][n]
    {
      const float* gp = W + (size_t)(kc + bkh * 16) * NHID + bn;
      bf16x8 p0, p1;
#pragma unroll
      for (int j = 0; j < 8; ++j) p0[j] = (__bf16)gp[(size_t)j * NHID];
#pragma unroll
      for (int j = 0; j < 8; ++j) p1[j] = (__bf16)gp[(size_t)(8 + j) * NHID];
      *reinterpret_cast<bf16x8*>(&Bs[bn][bkh * 16]) = p0;
      *reinterpret_cast<bf16x8*>(&Bs[bn][bkh * 16 + 8]) = p1;
    }
    __syncthreads();
    bf16x8 af[2], bfr[4];
#pragma unroll
    for (int m = 0; m < 2; ++m)
      af[m] = *reinterpret_cast<const bf16x8*>(&As[wm * 32 + m * 16 + lrow][lk]);
#pragma unroll
    for (int n = 0; n < 4; ++n)
      bfr[n] = *reinterpret_cast<const bf16x8*>(&Bs[wn * 64 + n * 16 + lrow][lk]);
#pragma unroll
    for (int m = 0; m < 2; ++m)
#pragma unroll
      for (int n = 0; n < 4; ++n)
        acc[m][n] = __builtin_amdgcn_mfma_f32_16x16x32_bf16(af[m], bfr[n], acc[m][n], 0, 0, 0);
    __syncthreads();
  }
  // epilogue: C/D layout col=lane&15, row=(lane>>4)*4+j; store sortable-u16
#pragma unroll
  for (int m = 0; m < 2; ++m) {
    int row0 = rb + wm * 32 + m * 16 + (lane >> 4) * 4;
#pragma unroll
    for (int n = 0; n < 4; ++n) {
      int col = wn * 64 + n * 16 + lrow;
#pragma unroll
      for (int j = 0; j < 4; ++j) {
        int r = row0 + j;
        if (r < N_NODES) H1[(size_t)r * NHID + col] = bf2sort(f2bf(acc[m][n][j]));
      }
    }
  }
}

// ======================= build_k: per-bucket CSR row construction in LDS =======================
// One block per 256-node bucket. LDS atomics for slot counters (no fabric txns),
// full-line uint4 writes of adjw rows + coalesced cur writes.

__global__ __launch_bounds__(256) void build_k(const int* __restrict__ gcnt,
                                               const uint_t* __restrict__ buf,
                                               int* __restrict__ cur,
                                               ushort_t* __restrict__ adjw) {
  __shared__ __attribute__((aligned(16))) ushort_t rows[256 * STRIDE];
  __shared__ int cnt[256];
  int b = blockIdx.x, tid = threadIdx.x;
  int v0 = b << 8;
  int nv = N_NODES - v0;
  if (nv > 256) nv = 256;
  cnt[tid] = 1;  // slot 0 = self loop
  if (tid < nv) rows[tid * STRIDE] = (ushort_t)(v0 + tid);
  __syncthreads();

  int n = gcnt[b];
  if (n > CAPB) n = CAPB;
  for (int i = tid; i < n; i += 256) {
    uint_t e = buf[(size_t)b * CAPB + i];
    int s = e & 0xFFFF;
    int doff = e >> 16;
    int p = atomicAdd(&cnt[doff], 1);
    if (p < STRIDE) rows[doff * STRIDE + p] = (ushort_t)s;
  }
  __syncthreads();

  int nq = nv * 6;  // uint4 per node: 48*2/16 = 6
  uint4* gout = reinterpret_cast<uint4*>(adjw + (size_t)v0 * STRIDE);
  const uint4* ls = reinterpret_cast<const uint4*>(rows);
  for (int i = tid; i < nq; i += 256) gout[i] = ls[i];
  if (tid < nv) cur[v0 + tid] = cnt[tid] - 1;
}

// ======================= GEMM2 (MFMA): h2 = X1(bf16) @ W2 -> sortable-u16 =======================
// 128-row tile x 32 cols, K=128 (4 steps), 4 waves (each 32 rows x 32 cols).

__global__ __launch_bounds__(256) void gemm2_k(const uint_t* __restrict__ X1u,
                                               const float* __restrict__ W,
                                               ushort_t* __restrict__ H2s) {
  __shared__ ushort_t As[128][136];  // [row][k] +8 pad
  __shared__ ushort_t Bs[32][136];   // [col][k] (W2 transposed)
  int tid = threadIdx.x;
  int rb = blockIdx.x * 128;
  int lane = tid & 63, wid = tid >> 6;
  int lrow = lane & 15, lk = (lane >> 4) * 8;

#pragma unroll
  for (int j = 0; j < 8; ++j) {
    int f = tid + j * 256;   // uint4 index
    int row = f >> 4;
    int q = f & 15;
    int grow = rb + row;
    uint4 v = make_uint4(0, 0, 0, 0);
    if (grow < N_NODES)
      v = *reinterpret_cast<const uint4*>(X1u + (size_t)grow * 64 + q * 4);
    *reinterpret_cast<uint4*>(&As[row][q * 8]) = v;
  }
  {
    int bn = tid & 31, bq = tid >> 5;
    const float* gp = W + (size_t)(bq * 16) * NCLASS + bn;
    bf16x8 p0, p1;
#pragma unroll
    for (int j = 0; j < 8; ++j) p0[j] = (__bf16)gp[(size_t)j * NCLASS];
#pragma unroll
    for (int j = 0; j < 8; ++j) p1[j] = (__bf16)gp[(size_t)(8 + j) * NCLASS];
    *reinterpret_cast<bf16x8*>(&Bs[bn][bq * 16]) = p0;
    *reinterpret_cast<bf16x8*>(&Bs[bn][bq * 16 + 8]) = p1;
  }
  __syncthreads();

  f32x4 acc[2][2];
#pragma unroll
  for (int m = 0; m < 2; ++m)
#pragma unroll
    for (int n = 0; n < 2; ++n) acc[m][n] = (f32x4){0.f, 0.f, 0.f, 0.f};

#pragma unroll
  for (int ks = 0; ks < 4; ++ks) {
    bf16x8 af[2], bfr[2];
#pragma unroll
    for (int m = 0; m < 2; ++m)
      af[m] = *reinterpret_cast<const bf16x8*>(&As[wid * 32 + m * 16 + lrow][ks * 32 + lk]);
#pragma unroll
    for (int n = 0; n < 2; ++n)
      bfr[n] = *reinterpret_cast<const bf16x8*>(&Bs[n * 16 + lrow][ks * 32 + lk]);
#pragma unroll
    for (int m = 0; m < 2; ++m)
#pragma unroll
      for (int n = 0; n < 2; ++n)
        acc[m][n] = __builtin_amdgcn_mfma_f32_16x16x32_bf16(af[m], bfr[n], acc[m][n], 0, 0, 0);
  }
#pragma unroll
  for (int m = 0; m < 2; ++m) {
    int row0 = rb + wid * 32 + m * 16 + (lane >> 4) * 4;
#pragma unroll
    for (int n = 0; n < 2; ++n) {
      int col = n * 16 + lrow;
#pragma unroll
      for (int j = 0; j < 4; ++j) {
        int r = row0 + j;
        if (r < N_NODES) H2s[(size_t)r * NCLASS + col] = bf2sort(f2bf(acc[m][n][j]));
      }
    }
  }
}

// ======================= packed-u16 Batcher sort (2 features per reg) =======================
// Valid for any NP: equals the next-pow2 odd-even mergesort network with comparators
// touching positions >= NP pruned (those positions provably hold +inf = 0xFFFF forever).

template <int NP>
__device__ __forceinline__ void pk_sort(u16x2 (&a)[NP]) {
#pragma unroll
  for (int p = 1; p < NP; p <<= 1) {
#pragma unroll
    for (int q = p; q >= 1; q >>= 1) {
#pragma unroll
      for (int j = q % p; j + q < NP; j += 2 * q) {
#pragma unroll
        for (int i = 0; i < q; ++i) {
          int lo = i + j, hi = i + j + q;
          if (hi < NP && (lo / (2 * p)) == (hi / (2 * p))) {
            u16x2 x = a[lo], y = a[hi];
            a[lo] = __builtin_elementwise_min(x, y);  // v_pk_min_u16
            a[hi] = __builtin_elementwise_max(x, y);  // v_pk_max_u16
          }
        }
      }
    }
  }
}

// ======================= Median layer 1 + bias + ReLU =======================
// ONE wave per node; lane t owns features {2t,2t+1} packed in one dword.
// k is wave-uniform (readfirstlane) -> e>=k gather loads are skipped scalar-ly.

template <int KP>
__device__ __forceinline__ uint_t med1_path(const uint_t* __restrict__ H1p, int sreg,
                                            int k, int m, int t) {
  u16x2 a[KP];
#pragma unroll
  for (int e = 0; e < KP; ++e) {
    uint_t pu = 0xFFFFFFFFu;  // pad sorts to end
    if (e < k) {              // wave-uniform branch: load skipped entirely when e>=k
      int s = __builtin_amdgcn_readlane(sreg, e);
      pu = H1p[(size_t)s * 64 + t];
    }
    union { uint_t u; u16x2 v; } c;
    c.u = pu;
    a[e] = c.v;
  }
  pk_sort<KP>(a);
  u16x2 med = a[0];
#pragma unroll
  for (int i = 1; i <= (KP - 1) / 2; ++i)
    if (i == m) med = a[i];  // wave-uniform m
  union { u16x2 v; uint_t u; } r;
  r.v = med;
  return r.u;
}

__global__ __launch_bounds__(256, 8) void med1_k(const ushort_t* __restrict__ H1,
                                                 const int* __restrict__ cur,
                                                 const ushort_t* __restrict__ adjw,
                                                 const float* __restrict__ b1,
                                                 uint_t* __restrict__ X1u) {
  int v = blockIdx.x * 4 + (threadIdx.x >> 6);
  int t = threadIdx.x & 63;
  int k = cur[v] + 1;
  if (k > STRIDE) k = STRIDE;
  k = __builtin_amdgcn_readfirstlane(k);  // wave-uniform -> SGPR
  int sreg = adjw[v * STRIDE + ((t < k) ? t : 0)];
  int m = (k - 1) >> 1;
  const uint_t* H1p = reinterpret_cast<const uint_t*>(H1);
  uint_t mu;
  if (k <= 16)      mu = med1_path<16>(H1p, sreg, k, m, t);
  else if (k <= 20) mu = med1_path<20>(H1p, sreg, k, m, t);
  else if (k <= 24) mu = med1_path<24>(H1p, sreg, k, m, t);
  else if (k <= 28) mu = med1_path<28>(H1p, sreg, k, m, t);
  else if (k <= 32) mu = med1_path<32>(H1p, sreg, k, m, t);
  else              mu = med1_path<48>(H1p, sreg, k, m, t);
  ushort_t s0 = (ushort_t)(mu & 0xFFFF), s1 = (ushort_t)(mu >> 16);
  float2 bb = *reinterpret_cast<const float2*>(b1 + 2 * t);
  float f0 = fmaxf(bf2f(sort2bf(s0)) + bb.x, 0.f);
  float f1 = fmaxf(bf2f(sort2bf(s1)) + bb.y, 0.f);
  X1u[(size_t)v * 64 + t] = (uint_t)f2bf(f0) | ((uint_t)f2bf(f1) << 16);
}

// ============ Median layer 2 (packed-u16) + bias + fused log_softmax ============
// 4 nodes per wave: 16-lane group per node, lane l owns classes {2l, 2l+1}.

template <int KP>
__device__ __forceinline__ uint_t med2_path(const uint_t* __restrict__ H2p,
                                            int s0, int s1, int s2,
                                            int k, int m, int g, int l) {
  u16x2 a[KP];
#pragma unroll
  for (int e = 0; e < KP; ++e) {
    int sr = (e < 16) ? s0 : ((e < 32) ? s1 : s2);
    int srcid = __shfl(sr, g * 16 + (e & 15), 64);  // group broadcast
    uint_t u = H2p[(size_t)srcid * 16 + l];
    uint_t pu = (e < k) ? u : 0xFFFFFFFFu;
    union { uint_t u; u16x2 v; } c;
    c.u = pu;
    a[e] = c.v;
  }
  pk_sort<KP>(a);
  u16x2 med = a[0];
#pragma unroll
  for (int i = 1; i <= (KP - 1) / 2; ++i)
    if (i == m) med = a[i];  // m uniform within group
  union { u16x2 v; uint_t u; } r;
  r.v = med;
  return r.u;
}

__global__ __launch_bounds__(256, 8) void med2_k(const ushort_t* __restrict__ H2,
                                                 const int* __restrict__ cur,
                                                 const ushort_t* __restrict__ adjw,
                                                 const float* __restrict__ b2,
                                                 float* __restrict__ OUT) {
  int w = threadIdx.x >> 6;
  int t = threadIdx.x & 63;
  int l = t & 15, g = t >> 4;  // group g in [0,4), lane l in group
  int vh = (blockIdx.x * 4 + w) * 4 + g;
  int k = cur[vh] + 1;
  if (k > STRIDE) k = STRIDE;
  int m = (k - 1) >> 1;
  // three adjacency slots per lane (u16 loads), clamped to valid range
  int base = vh * STRIDE;
  int s0 = adjw[base + ((l < k) ? l : 0)];
  int s1 = adjw[base + ((16 + l < k) ? 16 + l : 0)];
  int s2 = adjw[base + ((32 + l < k) ? 32 + l : 0)];
  // wave-wide kmax (k uniform within each 16-lane group)
  int kmax = max(k, __shfl_xor(k, 16, 64));
  kmax = max(kmax, __shfl_xor(kmax, 32, 64));
  const uint_t* H2p = reinterpret_cast<const uint_t*>(H2);
  uint_t mu;
  if (kmax <= 16)      mu = med2_path<16>(H2p, s0, s1, s2, k, m, g, l);
  else if (kmax <= 20) mu = med2_path<20>(H2p, s0, s1, s2, k, m, g, l);
  else if (kmax <= 24) mu = med2_path<24>(H2p, s0, s1, s2, k, m, g, l);
  else if (kmax <= 28) mu = med2_path<28>(H2p, s0, s1, s2, k, m, g, l);
  else if (kmax <= 32) mu = med2_path<32>(H2p, s0, s1, s2, k, m, g, l);
  else                 mu = med2_path<48>(H2p, s0, s1, s2, k, m, g, l);
  ushort_t u0 = (ushort_t)(mu & 0xFFFF), u1 = (ushort_t)(mu >> 16);
  float2 bb = *reinterpret_cast<const float2*>(b2 + 2 * l);
  float f0 = bf2f(sort2bf(u0)) + bb.x;
  float f1 = bf2f(sort2bf(u1)) + bb.y;
  // log_softmax over the 32 classes held by this 16-lane group
  float mx = fmaxf(f0, f1);
#pragma unroll
  for (int s = 8; s; s >>= 1) mx = fmaxf(mx, __shfl_xor(mx, s, 16));
  float sum = expf(f0 - mx) + expf(f1 - mx);
#pragma unroll
  for (int s = 8; s; s >>= 1) sum += __shfl_xor(sum, s, 16);
  float lg = logf(sum);
  float2 res = make_float2(f0 - mx - lg, f1 - mx - lg);
  *reinterpret_cast<float2*>(&OUT[(size_t)vh * NCLASS + 2 * l]) = res;
}

// ======================= launcher =======================

extern "C" void kernel_launch(void* const* d_in, const int* in_sizes, int n_in,
                              void* d_out, int out_size, void* d_ws, size_t ws_size,
                              hipStream_t stream) {
  const float* X = (const float*)d_in[0];
  const int* src = (const int*)d_in[1];
  const int* dst = src + N_EDGES;
  const float* W1 = (const float*)d_in[2];
  const float* b1 = (const float*)d_in[3];
  const float* W2 = (const float*)d_in[4];
  const float* b2 = (const float*)d_in[5];
  float* OUT = (float*)d_out;

  char* w = (char*)d_ws;
  size_t o = 0;
  auto take = [&](size_t bytes) {
    void* p = w + o;
    o += (bytes + 255) & ~(size_t)255;
    return p;
  };
  int* cur = (int*)take(N_NODES * sizeof(int));
  ushort_t* adjw = (ushort_t*)take((size_t)N_NODES * STRIDE * sizeof(ushort_t));
  ushort_t* h1 = (ushort_t*)take((size_t)N_NODES * NHID * sizeof(ushort_t));
  uint_t* x1 = (uint_t*)take((size_t)N_NODES * 64 * sizeof(uint_t));
  ushort_t* h2 = (ushort_t*)take((size_t)N_NODES * NCLASS * sizeof(ushort_t));
  int* gcnt = (int*)take(256 * sizeof(int));
  uint_t* buf = (uint_t*)take((size_t)NBKT * CAPB * sizeof(uint_t));
  (void)ws_size;

  hipMemsetAsync(gcnt, 0, 256 * sizeof(int), stream);
  pre_k<<<G1B + NTILE, 256, 0, stream>>>(X, W1, h1, src, dst, gcnt, buf);
  build_k<<<NBKT, 256, 0, stream>>>(gcnt, buf, cur, adjw);
  med1_k<<<N_NODES / 4, 256, 0, stream>>>(h1, cur, adjw, b1, x1);
  gemm2_k<<<(N_NODES + 127) / 128, 256, 0, stream>>>(x1, W2, h2);
  med2_k<<<N_NODES / 16, 256, 0, stream>>>(h2, cur, adjw, b2, OUT);
}